// Round 1
// baseline (1631.156 us; speedup 1.0000x reference)
//
#include <hip/hip_runtime.h>
#include <hip/hip_bf16.h>
#include <hip/hip_fp16.h>

// 2-layer GCN, N=100000 nodes, E=3.2M edges, dims 128 -> 64 -> 2, fp32.
// R14: windowed-gather aggregation. k_build now counting-sorts each dst-bucket's
// edge list by src (bin = src>>9) in place in ebuf; csw/rp per-node CSR dropped.
// k_aggB: one block per 128-node bucket, 32KB LDS fp32 accumulator, 8 waves
// walk the src-sorted list in lock-step stride -> all 782 blocks co-resident
// sweep a narrow h1 window that stays L2-resident per XCD (predicted FETCH
// 333MB -> ~150MB on the layer-1 aggregation). k_prop2 same structure (h2 is
// L2-hot anyway). k_hist/k_scan1/k_scan2/k_scatter/k_gemm1 unchanged from R13.

#define DIN  128
#define DHID 64
#define BSH  7                    // bucket shift: 128 nodes/bucket
#define BCAP 5000                 // k_build LDS staging capacity (edges)
#define SCHUNK 12544              // k_scatter LDS slot capacity (>= E/C)
#define BMAX 800                  // >= B = ceil(N/128) = 782
#define SB   9                    // src-sort bin shift: 512 nodes/bin
#define SBMAX 512                 // max src bins (N=100000 -> 196)

typedef _Float16 half8 __attribute__((ext_vector_type(8)));
typedef float    f32x4 __attribute__((ext_vector_type(4)));

// ---------------- K1: per-chunk coarse histogram (LDS only) --------
__global__ __launch_bounds__(1024) void k_hist(const int* __restrict__ ei,
                                               int* __restrict__ histT,
                                               int E, int chunk, int B, int C) {
    extern __shared__ int h[];
    for (int t = threadIdx.x; t < B; t += 1024) h[t] = 0;
    __syncthreads();
    int c = blockIdx.x;
    int e0 = c * chunk, e1 = min(E, e0 + chunk);
    for (int e = e0 + threadIdx.x; e < e1; e += 1024)
        atomicAdd(&h[ei[E + e] >> BSH], 1);
    __syncthreads();
    for (int t = threadIdx.x; t < B; t += 1024) histT[(size_t)t * C + c] = h[t];
}

// ------- K2: per-bucket exclusive scan over its C chunk-cells ------
__global__ __launch_bounds__(256) void k_scan1(int* __restrict__ histT,
                                               int* __restrict__ tot, int C) {
    __shared__ int sm[256];
    int b = blockIdx.x, t = threadIdx.x;
    size_t base = (size_t)b * C;
    int v = histT[base + t];
    sm[t] = v;
    __syncthreads();
    for (int off = 1; off < 256; off <<= 1) {
        int add = (t >= off) ? sm[t - off] : 0;
        __syncthreads();
        sm[t] += add;
        __syncthreads();
    }
    histT[base + t] = sm[t] - v;          // exclusive within bucket
    if (t == 255) tot[b] = sm[t];
}

// ------- K3: exclusive scan of bucket totals -> bucket bases -------
__global__ __launch_bounds__(1024) void k_scan2(const int* __restrict__ tot,
                                                int* __restrict__ bb, int B) {
    __shared__ int sm[1024];
    int t = threadIdx.x;
    int v = (t < B) ? tot[t] : 0;
    sm[t] = v;
    __syncthreads();
    for (int off = 1; off < 1024; off <<= 1) {
        int add = (t >= off) ? sm[t - off] : 0;
        __syncthreads();
        sm[t] += add;
        __syncthreads();
    }
    if (t < B) {
        bb[t] = sm[t] - v;
        if (t == B - 1) bb[B] = sm[t];
    }
}

// ---------------- K4: LDS slot-reordered scatter -------------------
// Per chunk: count -> scan -> place edge indices into bucket-ordered
// slots -> slot-ordered coalesced writeout to ebuf.
__global__ __launch_bounds__(1024) void k_scatter(const int* __restrict__ ei,
                                                  const float* __restrict__ ew,
                                                  const int* __restrict__ histT,
                                                  const int* __restrict__ bb,
                                                  int2* __restrict__ ebuf,
                                                  int E, int chunk, int B, int C) {
    __shared__ int eidx[SCHUNK];          // 50 KB (also scan temp)
    __shared__ int lbase[BMAX];
    __shared__ int lcur[BMAX];
    __shared__ int gbase[BMAX];
    int c = blockIdx.x, t = threadIdx.x;
    int e0 = c * chunk, e1 = min(E, e0 + chunk), m = e1 - e0;

    for (int b = t; b < B; b += 1024) lcur[b] = 0;
    __syncthreads();
    // pass 1: per-bucket counts
    for (int q = t; q < m; q += 1024)
        atomicAdd(&lcur[ei[E + e0 + q] >> BSH], 1);
    __syncthreads();
    // scan counts (1024-wide Hillis-Steele in eidx[0..1023])
    int v = (t < B) ? lcur[t] : 0;
    eidx[t] = v;
    __syncthreads();
    for (int off = 1; off < 1024; off <<= 1) {
        int add = (t >= off) ? eidx[t - off] : 0;
        __syncthreads();
        eidx[t] += add;
        __syncthreads();
    }
    if (t < B) {
        lbase[t] = eidx[t] - v;
        gbase[t] = histT[(size_t)t * C + c] + bb[t];
        lcur[t] = 0;
    }
    __syncthreads();
    // pass 2: place edge indices into bucket-ordered slots (dst re-read L2-hot)
    for (int q = t; q < m; q += 1024) {
        int b = ei[E + e0 + q] >> BSH;
        int pos = lbase[b] + atomicAdd(&lcur[b], 1);
        eidx[pos] = q;
    }
    __syncthreads();
    // pass 3: slot-ordered writeout (consecutive slots -> consecutive ebuf)
    for (int q = t; q < m; q += 1024) {
        int e = e0 + eidx[q];
        int s = ei[e];
        int d = ei[E + e];
        float w = ew[e];
        int b = d >> BSH;
        int gpos = gbase[b] + (q - lbase[b]);
        ebuf[gpos] = make_int2(s | ((d & 127) << 24), __float_as_int(w));
    }
}

// ---------------- K5: per-bucket dinv + in-place src counting sort -
// Stages the bucket's edges in LDS, accumulates per-local-node weighted
// degree (-> dinv), then counting-sorts the bucket's edge list by src
// bin (src>>SB) and writes it back in place. Sort is perf-only: it turns
// the layer-1/layer-2 gather streams into a monotone sweep of src space.
__global__ __launch_bounds__(512) void k_build(int2* __restrict__ ebuf,
                                               const int* __restrict__ bb,
                                               float* __restrict__ dinv,
                                               int N, int nb) {
    __shared__ int2  stage[BCAP];   // 40 KB
    __shared__ float dsum[128];
    __shared__ int   scnt[SBMAX];
    __shared__ int   sbase[SBMAX];
    __shared__ int   sm[512];
    int b = blockIdx.x, t = threadIdx.x;
    if (t < 128) dsum[t] = 0.0f;
    for (int q = t; q < nb; q += 512) scnt[q] = 0;
    __syncthreads();
    int p0 = bb[b], p1 = bb[b + 1];
    int m = p1 - p0;
    bool fits = (m <= BCAP) && (nb <= SBMAX);
    for (int p = p0 + t; p < p1; p += 512) {
        int2 v = ebuf[p];
        if (fits) stage[p - p0] = v;
        int ln = (((unsigned)v.x) >> 24) & 127;
        atomicAdd(&dsum[ln], __int_as_float(v.y));
        if (fits) atomicAdd(&scnt[(v.x & 0xFFFFFF) >> SB], 1);
    }
    __syncthreads();
    if (t < 128) {
        int d = (b << BSH) + t;
        if (d < N) dinv[d] = rsqrtf(1.0f + dsum[t]);
    }
    if (!fits) return;              // unsorted fallback (correct, slower)
    // branch-free 512-wide scan of nb bin counts
    int cv = (t < nb) ? scnt[t] : 0;
    sm[t] = cv;
    __syncthreads();
    for (int off = 1; off < 512; off <<= 1) {
        int add = (t >= off) ? sm[t - off] : 0;
        __syncthreads();
        sm[t] += add;
        __syncthreads();
    }
    if (t < nb) {
        sbase[t] = sm[t] - cv;      // exclusive base per src bin
        scnt[t] = 0;                // reuse as cursor
    }
    __syncthreads();
    // placement: write back src-bin-ordered (scatter within 32KB region, L2)
    for (int q = t; q < m; q += 512) {
        int2 v = stage[q];
        int bin = (v.x & 0xFFFFFF) >> SB;
        int pos = sbase[bin] + atomicAdd(&scnt[bin], 1);
        ebuf[p0 + pos] = v;
    }
}

// ---------------- K6: h1 = fp16(x @ W1) via MFMA (W1 conv inline) --
__global__ __launch_bounds__(256) void k_gemm1(const float* __restrict__ x,
                                               const float* __restrict__ W1,
                                               __half* __restrict__ h1, int N) {
    __shared__ _Float16 As[64][136];
    __shared__ _Float16 Bs[64][136];   // Bs[col][k]
    int t = threadIdx.x;
    int wave = t >> 6, lane = t & 63;
    int r0 = blockIdx.x * 64;

    for (int idx = t; idx < DIN * DHID; idx += 256) {
        int k = idx >> 6, c = idx & 63;
        Bs[c][k] = (_Float16)W1[idx];          // W1 32KB -> L2-resident
    }
    const float4* xv = (const float4*)x;
    for (int idx = t; idx < 64 * 32; idx += 256) {
        int r = idx >> 5, c4 = idx & 31;
        int rr = r0 + r;
        float4 v = (rr < N) ? xv[(size_t)rr * 32 + c4]
                            : make_float4(0.f, 0.f, 0.f, 0.f);
        As[r][c4 * 4 + 0] = (_Float16)v.x;
        As[r][c4 * 4 + 1] = (_Float16)v.y;
        As[r][c4 * 4 + 2] = (_Float16)v.z;
        As[r][c4 * 4 + 3] = (_Float16)v.w;
    }
    __syncthreads();

    int row = lane & 15;
    int kg  = lane >> 4;
    f32x4 acc0 = {0.f,0.f,0.f,0.f}, acc1 = {0.f,0.f,0.f,0.f};
    f32x4 acc2 = {0.f,0.f,0.f,0.f}, acc3 = {0.f,0.f,0.f,0.f};
#pragma unroll
    for (int kc = 0; kc < 4; ++kc) {
        half8 a = *(const half8*)&As[wave * 16 + row][kc * 32 + kg * 8];
        half8 b0 = *(const half8*)&Bs[ 0 + row][kc * 32 + kg * 8];
        half8 b1 = *(const half8*)&Bs[16 + row][kc * 32 + kg * 8];
        half8 b2 = *(const half8*)&Bs[32 + row][kc * 32 + kg * 8];
        half8 b3 = *(const half8*)&Bs[48 + row][kc * 32 + kg * 8];
        acc0 = __builtin_amdgcn_mfma_f32_16x16x32_f16(a, b0, acc0, 0, 0, 0);
        acc1 = __builtin_amdgcn_mfma_f32_16x16x32_f16(a, b1, acc1, 0, 0, 0);
        acc2 = __builtin_amdgcn_mfma_f32_16x16x32_f16(a, b2, acc2, 0, 0, 0);
        acc3 = __builtin_amdgcn_mfma_f32_16x16x32_f16(a, b3, acc3, 0, 0, 0);
    }
#pragma unroll
    for (int reg = 0; reg < 4; ++reg) {
        int rr = r0 + wave * 16 + kg * 4 + reg;
        if (rr < N) {
            int col = lane & 15;
            size_t base = (size_t)rr * DHID;
            h1[base + col +  0] = __float2half(acc0[reg]);
            h1[base + col + 16] = __float2half(acc1[reg]);
            h1[base + col + 32] = __float2half(acc2[reg]);
            h1[base + col + 48] = __float2half(acc3[reg]);
        }
    }
}

// ------- K7: layer-1 aggregate, bucket-block windowed gather -------
// One block per 128-node dst bucket; 8 waves stride the src-sorted edge
// list in lock-step (all 782 blocks co-resident -> chip-wide moving src
// window keeps h1 gathers L2-hot). LDS fp32 accumulator; epilogue fuses
// +self +b1 +ReLU +@W2 -> h2.
__global__ __launch_bounds__(512) void k_aggB(const __half* __restrict__ h1h,
                                              const int2* __restrict__ ebuf,
                                              const int* __restrict__ bb,
                                              const float* __restrict__ dinv,
                                              const float* __restrict__ b1,
                                              const float* __restrict__ W2,
                                              float* __restrict__ h2, int N) {
    __shared__ float accs[128 * DHID];   // 32 KB
    int b = blockIdx.x, t = threadIdx.x;
    int wid = t >> 6, lane = t & 63;
    for (int q = t; q < 128 * DHID; q += 512) accs[q] = 0.0f;
    __syncthreads();
    int p0 = bb[b], p1 = bb[b + 1], m = p1 - p0;
    int q = wid;
    // 4-edge unroll per wave; waves interleave stride-8 so the whole block
    // (and chip) sweeps the sorted src range together.
    for (; q + 24 < m; q += 32) {
        int2 eA = ebuf[p0 + q];
        int2 eB = ebuf[p0 + q + 8];
        int2 eC = ebuf[p0 + q + 16];
        int2 eD = ebuf[p0 + q + 24];
        int xA = __builtin_amdgcn_readfirstlane(eA.x);
        int xB = __builtin_amdgcn_readfirstlane(eB.x);
        int xC = __builtin_amdgcn_readfirstlane(eC.x);
        int xD = __builtin_amdgcn_readfirstlane(eD.x);
        int sA = xA & 0xFFFFFF, dA = (xA >> 24) & 127;
        int sB = xB & 0xFFFFFF, dB = (xB >> 24) & 127;
        int sC = xC & 0xFFFFFF, dC = (xC >> 24) & 127;
        int sD = xD & 0xFFFFFF, dD = (xD >> 24) & 127;
        float wA = __uint_as_float(__builtin_amdgcn_readfirstlane(eA.y)) * dinv[sA];
        float wB = __uint_as_float(__builtin_amdgcn_readfirstlane(eB.y)) * dinv[sB];
        float wC = __uint_as_float(__builtin_amdgcn_readfirstlane(eC.y)) * dinv[sC];
        float wD = __uint_as_float(__builtin_amdgcn_readfirstlane(eD.y)) * dinv[sD];
        float hA = __half2float(h1h[(size_t)sA * DHID + lane]);
        float hB = __half2float(h1h[(size_t)sB * DHID + lane]);
        float hC = __half2float(h1h[(size_t)sC * DHID + lane]);
        float hD = __half2float(h1h[(size_t)sD * DHID + lane]);
        atomicAdd(&accs[dA * DHID + lane], wA * hA);
        atomicAdd(&accs[dB * DHID + lane], wB * hB);
        atomicAdd(&accs[dC * DHID + lane], wC * hC);
        atomicAdd(&accs[dD * DHID + lane], wD * hD);
    }
    for (; q < m; q += 8) {
        int2 eA = ebuf[p0 + q];
        int xA = __builtin_amdgcn_readfirstlane(eA.x);
        int sA = xA & 0xFFFFFF, dA = (xA >> 24) & 127;
        float wA = __uint_as_float(__builtin_amdgcn_readfirstlane(eA.y)) * dinv[sA];
        float hA = __half2float(h1h[(size_t)sA * DHID + lane]);
        atomicAdd(&accs[dA * DHID + lane], wA * hA);
    }
    __syncthreads();
    // epilogue: acc = di*(edge_sum + di*self); +b1, ReLU, @W2 -> h2[i][0..1]
    float bias = b1[lane];
    float w2a = W2[lane * 2];
    float w2b = W2[lane * 2 + 1];
    for (int ln = wid; ln < 128; ln += 8) {
        int i = (b << BSH) + ln;
        if (i >= N) continue;
        float di = dinv[i];
        float self = __half2float(h1h[(size_t)i * DHID + lane]);
        float a = di * (accs[ln * DHID + lane] + di * self);
        a = fmaxf(a + bias, 0.0f);
        float o0 = a * w2a, o1 = a * w2b;
        for (int off = 32; off > 0; off >>= 1) {
            o0 += __shfl_xor(o0, off);
            o1 += __shfl_xor(o1, off);
        }
        if (lane == 0) {
            h2[i * 2]     = o0;
            h2[i * 2 + 1] = o1;
        }
    }
}

// ------- K8: layer-2 propagate, bucket-block (h2 is L2-hot) --------
__global__ __launch_bounds__(512) void k_prop2(const float* __restrict__ h2,
                                               const int2* __restrict__ ebuf,
                                               const int* __restrict__ bb,
                                               const float* __restrict__ dinv,
                                               const float* __restrict__ b2,
                                               float* __restrict__ out, int N) {
    __shared__ float acc[128][2];
    int b = blockIdx.x, t = threadIdx.x;
    if (t < 256) ((float*)acc)[t] = 0.0f;
    __syncthreads();
    int p0 = bb[b], p1 = bb[b + 1];
    const float2* h2v = (const float2*)h2;
    for (int p = p0 + t; p < p1; p += 512) {
        int2 ed = ebuf[p];
        int s  = ed.x & 0xFFFFFF;
        int dl = (((unsigned)ed.x) >> 24) & 127;
        float w = __int_as_float(ed.y) * dinv[s];
        float2 hv = h2v[s];
        atomicAdd(&acc[dl][0], w * hv.x);
        atomicAdd(&acc[dl][1], w * hv.y);
    }
    __syncthreads();
    if (t < 256) {
        int ln = t >> 1, d = t & 1;
        int i = (b << BSH) + ln;
        if (i < N) {
            float di = dinv[i];
            out[i * 2 + d] = di * (acc[ln][d] + di * h2[i * 2 + d]) + b2[d];
        }
    }
}

extern "C" void kernel_launch(void* const* d_in, const int* in_sizes, int n_in,
                              void* d_out, int out_size, void* d_ws, size_t ws_size,
                              hipStream_t stream) {
    const float* x  = (const float*)d_in[0];
    const int*   ei = (const int*)d_in[1];     // int32 per harness contract
    const float* ew = (const float*)d_in[2];
    const float* W1 = (const float*)d_in[3];
    const float* b1 = (const float*)d_in[4];
    const float* W2 = (const float*)d_in[5];
    const float* b2 = (const float*)d_in[6];
    float* out = (float*)d_out;

    const int N = in_sizes[0] / DIN;   // 100000
    const int E = in_sizes[2];         // 3200000

    const int C = 256;                 // edge chunks (12.5K edges each)
    const int B = (N + 127) >> BSH;    // 782 buckets of 128 nodes
    const int chunk = (E + C - 1) / C;
    const int nb = (N + (1 << SB) - 1) >> SB;  // src bins (196)

    // workspace layout (~41 MB, no aliasing)
    char* w0 = (char*)d_ws;
    float* dinv  = (float*)w0;                      // N floats
    int*   histT = (int*)(dinv + N);                // B*C ints (800 KB)
    int*   tot   = histT + (size_t)B * C;           // B ints
    int*   bb    = tot + B;                         // B+1 ints
    size_t off_eb = ((size_t)((char*)(bb + B + 1) - w0) + 15) & ~(size_t)15;
    int2*  ebuf = (int2*)(w0 + off_eb);             // E pairs (25.6 MB)
    __half* h1  = (__half*)(ebuf + E);              // N*64 fp16 (12.8 MB)
    float* h2   = (float*)(h1 + (size_t)N * DHID);  // N*2 fp32 (0.8 MB)

    size_t ldsB = (size_t)B * sizeof(int);

    k_hist<<<C, 1024, ldsB, stream>>>(ei, histT, E, chunk, B, C);
    k_scan1<<<B, 256, 0, stream>>>(histT, tot, C);
    k_scan2<<<1, 1024, 0, stream>>>(tot, bb, B);
    k_scatter<<<C, 1024, 0, stream>>>(ei, ew, histT, bb, ebuf, E, chunk, B, C);
    k_build<<<B, 512, 0, stream>>>(ebuf, bb, dinv, N, nb);

    const int GB = (N + 63) / 64;
    k_gemm1<<<GB, 256, 0, stream>>>(x, W1, h1, N);

    k_aggB<<<B, 512, 0, stream>>>(h1, ebuf, bb, dinv, b1, W2, h2, N);
    k_prop2<<<B, 512, 0, stream>>>(h2, ebuf, bb, dinv, b2, out, N);
}

// Round 2
// 565.326 us; speedup vs baseline: 2.8853x; 2.8853x over previous
//
#include <hip/hip_runtime.h>
#include <hip/hip_bf16.h>
#include <hip/hip_fp16.h>

// 2-layer GCN, N=100000 nodes, E=3.2M edges, dims 128 -> 64 -> 2, fp32.
// R15: revert to R13's proven high-TLP structure (one wave per dst node,
// per-node CSR via rp/csw); replace the single 128B-gather k_agg1 with 4
// feature-chunked passes (k_aggP): h1 stored as h1c[4][N][16] fp16 (32B rows,
// 3.2MB/chunk -> per-XCD-L2-resident per pass). Each pass: 8 edges x 8
// feature-pairs per wave (half2 gathers, lane-coalesced edge loads). Pass 0
// folds wn=w*dinv[src] into csw.y (kills random dinv gathers in passes 1-3
// and k_prop2) and plain-stores h2; passes 1-3 atomicAdd. ReLU+b1+W2 epilogue
// fused per pass (P never hits HBM). h1c aliases ebuf; h2 aliases histT.

#define DIN  128
#define DHID 64
#define BSH  7                    // bucket shift: 128 nodes/bucket
#define BCAP 5000                 // k_build LDS staging capacity (edges)
#define SCHUNK 12544              // k_scatter LDS slot capacity (>= E/C)
#define BMAX 800                  // >= B = ceil(N/128) = 782

typedef _Float16 half8 __attribute__((ext_vector_type(8)));
typedef float    f32x4 __attribute__((ext_vector_type(4)));

// ---------------- K1: per-chunk coarse histogram (LDS only) --------
__global__ __launch_bounds__(1024) void k_hist(const int* __restrict__ ei,
                                               int* __restrict__ histT,
                                               int E, int chunk, int B, int C) {
    extern __shared__ int h[];
    for (int t = threadIdx.x; t < B; t += 1024) h[t] = 0;
    __syncthreads();
    int c = blockIdx.x;
    int e0 = c * chunk, e1 = min(E, e0 + chunk);
    for (int e = e0 + threadIdx.x; e < e1; e += 1024)
        atomicAdd(&h[ei[E + e] >> BSH], 1);
    __syncthreads();
    for (int t = threadIdx.x; t < B; t += 1024) histT[(size_t)t * C + c] = h[t];
}

// ------- K2: per-bucket exclusive scan over its C chunk-cells ------
__global__ __launch_bounds__(256) void k_scan1(int* __restrict__ histT,
                                               int* __restrict__ tot, int C) {
    __shared__ int sm[256];
    int b = blockIdx.x, t = threadIdx.x;
    size_t base = (size_t)b * C;
    int v = histT[base + t];
    sm[t] = v;
    __syncthreads();
    for (int off = 1; off < 256; off <<= 1) {
        int add = (t >= off) ? sm[t - off] : 0;
        __syncthreads();
        sm[t] += add;
        __syncthreads();
    }
    histT[base + t] = sm[t] - v;          // exclusive within bucket
    if (t == 255) tot[b] = sm[t];
}

// ------- K3: exclusive scan of bucket totals -> bucket bases -------
__global__ __launch_bounds__(1024) void k_scan2(const int* __restrict__ tot,
                                                int* __restrict__ bb, int B) {
    __shared__ int sm[1024];
    int t = threadIdx.x;
    int v = (t < B) ? tot[t] : 0;
    sm[t] = v;
    __syncthreads();
    for (int off = 1; off < 1024; off <<= 1) {
        int add = (t >= off) ? sm[t - off] : 0;
        __syncthreads();
        sm[t] += add;
        __syncthreads();
    }
    if (t < B) {
        bb[t] = sm[t] - v;
        if (t == B - 1) bb[B] = sm[t];
    }
}

// ---------------- K4: LDS slot-reordered scatter -------------------
__global__ __launch_bounds__(1024) void k_scatter(const int* __restrict__ ei,
                                                  const float* __restrict__ ew,
                                                  const int* __restrict__ histT,
                                                  const int* __restrict__ bb,
                                                  int2* __restrict__ ebuf,
                                                  int E, int chunk, int B, int C) {
    __shared__ int eidx[SCHUNK];          // 50 KB (also scan temp)
    __shared__ int lbase[BMAX];
    __shared__ int lcur[BMAX];
    __shared__ int gbase[BMAX];
    int c = blockIdx.x, t = threadIdx.x;
    int e0 = c * chunk, e1 = min(E, e0 + chunk), m = e1 - e0;

    for (int b = t; b < B; b += 1024) lcur[b] = 0;
    __syncthreads();
    // pass 1: per-bucket counts
    for (int q = t; q < m; q += 1024)
        atomicAdd(&lcur[ei[E + e0 + q] >> BSH], 1);
    __syncthreads();
    // scan counts (1024-wide Hillis-Steele in eidx[0..1023])
    int v = (t < B) ? lcur[t] : 0;
    eidx[t] = v;
    __syncthreads();
    for (int off = 1; off < 1024; off <<= 1) {
        int add = (t >= off) ? eidx[t - off] : 0;
        __syncthreads();
        eidx[t] += add;
        __syncthreads();
    }
    if (t < B) {
        lbase[t] = eidx[t] - v;
        gbase[t] = histT[(size_t)t * C + c] + bb[t];
        lcur[t] = 0;
    }
    __syncthreads();
    // pass 2: place edge indices into bucket-ordered slots
    for (int q = t; q < m; q += 1024) {
        int b = ei[E + e0 + q] >> BSH;
        int pos = lbase[b] + atomicAdd(&lcur[b], 1);
        eidx[pos] = q;
    }
    __syncthreads();
    // pass 3: slot-ordered writeout (consecutive slots -> consecutive ebuf)
    for (int q = t; q < m; q += 1024) {
        int e = e0 + eidx[q];
        int s = ei[e];
        int d = ei[E + e];
        float w = ew[e];
        int b = d >> BSH;
        int gpos = gbase[b] + (q - lbase[b]);
        ebuf[gpos] = make_int2(s | ((d & 127) << 24), __float_as_int(w));
    }
}

// ---------------- K5: per-bucket CSR build (rp, dinv, csw) ---------
__global__ __launch_bounds__(512) void k_build(const int2* __restrict__ ebuf,
                                               const int* __restrict__ bb,
                                               int* __restrict__ rp,
                                               float* __restrict__ dinv,
                                               int2* __restrict__ csw,
                                               int N, int E) {
    __shared__ int2  stage[BCAP];   // 40 KB
    __shared__ int   cnt[128];
    __shared__ float dsum[128];
    __shared__ int   lrp[128];
    __shared__ int   cur[128];
    __shared__ int   sm[512];
    int b = blockIdx.x, t = threadIdx.x;
    if (t < 128) { cnt[t] = 0; dsum[t] = 0.0f; cur[t] = 0; }
    __syncthreads();
    int p0 = bb[b], p1 = bb[b + 1];
    int m = p1 - p0;
    bool fits = (m <= BCAP);
    for (int p = p0 + t; p < p1; p += 512) {
        int2 v = ebuf[p];
        if (fits) stage[p - p0] = v;
        int ln = (((unsigned)v.x) >> 24) & 127;
        atomicAdd(&cnt[ln], 1);
        atomicAdd(&dsum[ln], __int_as_float(v.y));
    }
    __syncthreads();
    // branch-free scan of 128 counts (threads >=128 carry zeros)
    int cv = (t < 128) ? cnt[t] : 0;
    sm[t] = cv;
    __syncthreads();
    for (int off = 1; off < 128; off <<= 1) {
        int add = (t >= off) ? sm[t - off] : 0;
        __syncthreads();
        sm[t] += add;
        __syncthreads();
    }
    if (t < 128) {
        lrp[t] = sm[t] - cv + p0;     // absolute csw base for local node t
        int d = (b << BSH) + t;
        if (d < N) {
            rp[d]   = lrp[t];
            dinv[d] = rsqrtf(1.0f + dsum[t]);
        }
    }
    if (b == 0 && t == 0) rp[N] = E;
    __syncthreads();
    for (int q = t; q < m; q += 512) {
        int2 v = fits ? stage[q] : ebuf[p0 + q];
        int ln = (((unsigned)v.x) >> 24) & 127;
        int r = atomicAdd(&cur[ln], 1);   // LDS atomic
        csw[lrp[ln] + r] = make_int2(v.x & 0xFFFFFF, v.y);  // raw w
    }
}

// ---------------- K6: h1c = fp16(x @ W1), feature-chunked layout ---
// h1c[4][N][16]: chunk c holds features [16c,16c+16) as 32B rows.
__global__ __launch_bounds__(256) void k_gemm1(const float* __restrict__ x,
                                               const float* __restrict__ W1,
                                               __half* __restrict__ h1c, int N) {
    __shared__ _Float16 As[64][136];
    __shared__ _Float16 Bs[64][136];   // Bs[col][k]
    int t = threadIdx.x;
    int wave = t >> 6, lane = t & 63;
    int r0 = blockIdx.x * 64;

    for (int idx = t; idx < DIN * DHID; idx += 256) {
        int k = idx >> 6, c = idx & 63;
        Bs[c][k] = (_Float16)W1[idx];          // W1 32KB -> L2-resident
    }
    const float4* xv = (const float4*)x;
    for (int idx = t; idx < 64 * 32; idx += 256) {
        int r = idx >> 5, c4 = idx & 31;
        int rr = r0 + r;
        float4 v = (rr < N) ? xv[(size_t)rr * 32 + c4]
                            : make_float4(0.f, 0.f, 0.f, 0.f);
        As[r][c4 * 4 + 0] = (_Float16)v.x;
        As[r][c4 * 4 + 1] = (_Float16)v.y;
        As[r][c4 * 4 + 2] = (_Float16)v.z;
        As[r][c4 * 4 + 3] = (_Float16)v.w;
    }
    __syncthreads();

    int row = lane & 15;
    int kg  = lane >> 4;
    f32x4 acc0 = {0.f,0.f,0.f,0.f}, acc1 = {0.f,0.f,0.f,0.f};
    f32x4 acc2 = {0.f,0.f,0.f,0.f}, acc3 = {0.f,0.f,0.f,0.f};
#pragma unroll
    for (int kc = 0; kc < 4; ++kc) {
        half8 a = *(const half8*)&As[wave * 16 + row][kc * 32 + kg * 8];
        half8 b0 = *(const half8*)&Bs[ 0 + row][kc * 32 + kg * 8];
        half8 b1 = *(const half8*)&Bs[16 + row][kc * 32 + kg * 8];
        half8 b2 = *(const half8*)&Bs[32 + row][kc * 32 + kg * 8];
        half8 b3 = *(const half8*)&Bs[48 + row][kc * 32 + kg * 8];
        acc0 = __builtin_amdgcn_mfma_f32_16x16x32_f16(a, b0, acc0, 0, 0, 0);
        acc1 = __builtin_amdgcn_mfma_f32_16x16x32_f16(a, b1, acc1, 0, 0, 0);
        acc2 = __builtin_amdgcn_mfma_f32_16x16x32_f16(a, b2, acc2, 0, 0, 0);
        acc3 = __builtin_amdgcn_mfma_f32_16x16x32_f16(a, b3, acc3, 0, 0, 0);
    }
    size_t cb = (size_t)N * 16;            // chunk stride (halves)
#pragma unroll
    for (int reg = 0; reg < 4; ++reg) {
        int rr = r0 + wave * 16 + kg * 4 + reg;
        if (rr < N) {
            int col = lane & 15;
            size_t base = (size_t)rr * 16 + col;
            h1c[0 * cb + base] = __float2half(acc0[reg]);
            h1c[1 * cb + base] = __float2half(acc1[reg]);
            h1c[2 * cb + base] = __float2half(acc2[reg]);
            h1c[3 * cb + base] = __float2half(acc3[reg]);
        }
    }
}

// ------- K7: layer-1 aggregate, one feature-chunk per launch -------
// One wave per dst node (R13 structure). Lane = (edge slot j = lane>>3,
// feature pair k = lane&7). Gathers half2 (4B) from the 3.2MB L2-resident
// chunk; csw read lane-coalesced (nontemporal, 1x64B per 8 edges). Pass 0
// computes wn = w*dinv[src], stores it back into csw.y, and plain-stores
// h2; passes 1-3 read wn directly and atomicAdd. Fused b1+ReLU+W2 epilogue.
__global__ __launch_bounds__(256) void k_aggP(const __half* __restrict__ h1c,
                                              const int* __restrict__ rp,
                                              int2* __restrict__ csw,
                                              const float* __restrict__ dinv,
                                              const float* __restrict__ b1,
                                              const float* __restrict__ W2,
                                              float* __restrict__ h2,
                                              int N, int chunk) {
    int lane = threadIdx.x & 63;
    int i = (blockIdx.x * 256 + threadIdx.x) >> 6;
    if (i >= N) return;
    int j = lane >> 3;               // edge slot 0..7
    int k = lane & 7;                // feature pair -> features 2k,2k+1
    const __half2* hb = (const __half2*)(h1c + (size_t)chunk * ((size_t)N * 16));
    const long long* cq = (const long long*)csw;
    int s0 = __builtin_amdgcn_readfirstlane(rp[i]);
    int e0 = __builtin_amdgcn_readfirstlane(rp[i + 1]);
    float a0 = 0.f, a1 = 0.f;
    if (chunk == 0) {
        for (int p = s0; p < e0; p += 8) {
            int pe = p + j;
            bool ok = pe < e0;
            long long ev = ok ? __builtin_nontemporal_load(cq + pe) : 0LL;
            int s = (int)(ev & 0xFFFFFF);
            float wn = __int_as_float((int)(ev >> 32)) * dinv[s];
            if (ok && k == 0) ((int*)csw)[2 * pe + 1] = __float_as_int(wn);
            float2 hf = __half22float2(hb[(size_t)s * 8 + k]);
            a0 = fmaf(wn, hf.x, a0);
            a1 = fmaf(wn, hf.y, a1);
        }
    } else {
        for (int p = s0; p < e0; p += 8) {
            int pe = p + j;
            long long ev = (pe < e0) ? __builtin_nontemporal_load(cq + pe) : 0LL;
            int s = (int)(ev & 0xFFFFFF);
            float wn = __int_as_float((int)(ev >> 32));
            float2 hf = __half22float2(hb[(size_t)s * 8 + k]);
            a0 = fmaf(wn, hf.x, a0);
            a1 = fmaf(wn, hf.y, a1);
        }
    }
    // reduce over edge slots j (offsets 8,16,32)
    for (int off = 8; off < 64; off <<= 1) {
        a0 += __shfl_xor(a0, off);
        a1 += __shfl_xor(a1, off);
    }
    // self term: + di * h1c[chunk][i][2k..2k+1]
    float di = dinv[i];
    float2 sf = __half22float2(hb[(size_t)i * 8 + k]);
    a0 = fmaf(di, sf.x, a0);
    a1 = fmaf(di, sf.y, a1);
    // per-feature epilogue: a = relu(di*P + b1); partial h2 = a @ W2
    int f0 = chunk * 16 + 2 * k, f1 = f0 + 1;
    float r0 = fmaxf(fmaf(di, a0, b1[f0]), 0.0f);
    float r1 = fmaxf(fmaf(di, a1, b1[f1]), 0.0f);
    float o0 = r0 * W2[f0 * 2]     + r1 * W2[f1 * 2];
    float o1 = r0 * W2[f0 * 2 + 1] + r1 * W2[f1 * 2 + 1];
    // reduce over feature pairs k (offsets 1,2,4)
    for (int off = 1; off < 8; off <<= 1) {
        o0 += __shfl_xor(o0, off);
        o1 += __shfl_xor(o1, off);
    }
    if (lane == 0) {
        if (chunk == 0) {
            h2[i * 2]     = o0;        // pass 0 initializes (no memset)
            h2[i * 2 + 1] = o1;
        } else {
            atomicAdd(&h2[i * 2],     o0);
            atomicAdd(&h2[i * 2 + 1], o1);
        }
    }
}

// ------- K8: layer-2 propagate: out = di*(sum + di*self) + b2 ------
// csw.y already holds wn = w*dinv[src] (written by k_aggP pass 0).
__global__ __launch_bounds__(256) void k_prop2(const float* __restrict__ h2,
                                               const int* __restrict__ rp,
                                               const int2* __restrict__ csw,
                                               const float* __restrict__ dinv,
                                               const float* __restrict__ b2,
                                               float* __restrict__ out, int N) {
    const float2* h2v = (const float2*)h2;
    int lane = threadIdx.x & 63;
    int i = (blockIdx.x * 256 + threadIdx.x) >> 6;
    if (i >= N) return;
    int s0 = rp[i], e0 = rp[i + 1];
    float a0 = 0.0f, a1 = 0.0f;
    for (int p = s0 + lane; p < e0; p += 64) {
        int2 ed = csw[p];
        float w = __int_as_float(ed.y);       // wn = raw_w * dinv[src]
        float2 hv = h2v[ed.x];
        a0 = fmaf(w, hv.x, a0);
        a1 = fmaf(w, hv.y, a1);
    }
    for (int off = 32; off > 0; off >>= 1) {
        a0 += __shfl_xor(a0, off);
        a1 += __shfl_xor(a1, off);
    }
    if (lane == 0) {
        float di = dinv[i];
        out[i * 2]     = di * (a0 + di * h2[i * 2])     + b2[0];
        out[i * 2 + 1] = di * (a1 + di * h2[i * 2 + 1]) + b2[1];
    }
}

extern "C" void kernel_launch(void* const* d_in, const int* in_sizes, int n_in,
                              void* d_out, int out_size, void* d_ws, size_t ws_size,
                              hipStream_t stream) {
    const float* x  = (const float*)d_in[0];
    const int*   ei = (const int*)d_in[1];     // int32 per harness contract
    const float* ew = (const float*)d_in[2];
    const float* W1 = (const float*)d_in[3];
    const float* b1 = (const float*)d_in[4];
    const float* W2 = (const float*)d_in[5];
    const float* b2 = (const float*)d_in[6];
    float* out = (float*)d_out;

    const int N = in_sizes[0] / DIN;   // 100000
    const int E = in_sizes[2];         // 3200000

    const int C = 256;                 // edge chunks (12.5K edges each)
    const int B = (N + 127) >> BSH;    // 782 buckets of 128 nodes
    const int chunk = (E + C - 1) / C;

    // workspace layout (~53 MB; same footprint as R13)
    char* w0 = (char*)d_ws;
    float* dinv  = (float*)w0;                      // N floats
    int*   rp    = (int*)(dinv + N);                // N+1 ints (+3 pad)
    int*   histT = rp + (N + 4);                    // B*C ints (800 KB)
    int*   tot   = histT + (size_t)B * C;           // B ints
    int*   bb    = tot + B;                         // B+1 ints
    size_t off_csw = ((size_t)((char*)(bb + B + 1) - w0) + 15) & ~(size_t)15;
    int2*  csw  = (int2*)(w0 + off_csw);            // E pairs (25.6 MB)
    int2*  ebuf = csw + E;                          // E pairs (25.6 MB)
    __half* h1c = (__half*)ebuf;                    // alias: 4*N*16 fp16 (12.8 MB)
    float* h2   = (float*)histT;                    // alias: N*2 fp32 (800 KB)

    size_t ldsB = (size_t)B * sizeof(int);

    k_hist<<<C, 1024, ldsB, stream>>>(ei, histT, E, chunk, B, C);
    k_scan1<<<B, 256, 0, stream>>>(histT, tot, C);
    k_scan2<<<1, 1024, 0, stream>>>(tot, bb, B);
    k_scatter<<<C, 1024, 0, stream>>>(ei, ew, histT, bb, ebuf, E, chunk, B, C);
    k_build<<<B, 512, 0, stream>>>(ebuf, bb, rp, dinv, csw, N, E);

    const int GB = (N + 63) / 64;
    k_gemm1<<<GB, 256, 0, stream>>>(x, W1, h1c, N);

    const int GW = ((size_t)N * 64 + 255) / 256;   // one wave per node
    for (int c = 0; c < 4; ++c)
        k_aggP<<<GW, 256, 0, stream>>>(h1c, rp, csw, dinv, b1, W2, h2, N, c);
    k_prop2<<<GW, 256, 0, stream>>>(h2, rp, csw, dinv, b2, out, N);
}